// Round 15
// baseline (339.038 us; speedup 1.0000x reference)
//
#include <hip/hip_runtime.h>
#include <hip/hip_bf16.h>

#define HH 1024
#define AA 512
#define BB 32
#define SS 1024
#define TN 1024
#define M_ENC (SS*BB)
#define M_TOT ((SS+TN)*BB)
#define NCH 8

// e1_gemm LDS: 3 A buffers (8KB each: 64 rows x 64B x 2 k-halves) + lred 2KB
#define AB0 0
#define AB1 8192
#define AB2 16384
#define LRED 24576

typedef __attribute__((ext_vector_type(8))) short short8;
typedef __attribute__((ext_vector_type(4))) float f4;

union bfu { __hip_bfloat16 h; unsigned short u; };
__device__ __forceinline__ unsigned int f2bu(float x) {
  bfu t; t.h = __float2bfloat16(x); return (unsigned int)t.u;
}
__device__ __forceinline__ unsigned short f2b(float x) {
  bfu t; t.h = __float2bfloat16(x); return t.u;
}
__device__ __forceinline__ float tanh_fast(float x) {
  float e = __expf(2.f * x);
  return 1.f - 2.f / (e + 1.f);
}

// ---- merged prep: W1/W5 -> bf16 fragment-order repack + poly coefficients --
// blocks 0..255: W1; 256..511: W5; block 512: poly.
// Wc layout: frag id t = ((kb*32 + rg)*64 + lane), 8 bf16 per frag,
// fragment holds W[rg*16 + (lane&15)][kb*32 + (lane>>4)*8 + j].
__global__ void prep_all(const float* __restrict__ W1, const float* __restrict__ W5,
                         const float* __restrict__ W3, const float* __restrict__ W4,
                         unsigned short* __restrict__ W1c, unsigned short* __restrict__ W5c,
                         float* __restrict__ C) {
  if (blockIdx.x < 512) {
    const float* __restrict__ W = (blockIdx.x < 256) ? W1 : W5;
    unsigned short* __restrict__ Wc = (blockIdx.x < 256) ? W1c : W5c;
    const int t = (blockIdx.x & 255) * 256 + threadIdx.x;   // 0..65535
    const int lane = t & 63;
    const int rg = (t >> 6) & 31;
    const int kb = t >> 11;
    const int row = rg * 16 + (lane & 15);
    const int k = kb * 32 + ((lane >> 4) << 3);
    const float* src = W + (size_t)row * HH + k;
    f4 v0 = *(const f4*)(src);
    f4 v1 = *(const f4*)(src + 4);
    short8 o;
    o[0] = f2b(v0[0]); o[1] = f2b(v0[1]); o[2] = f2b(v0[2]); o[3] = f2b(v0[3]);
    o[4] = f2b(v1[0]); o[5] = f2b(v1[1]); o[6] = f2b(v1[2]); o[7] = f2b(v1[3]);
    *(short8*)(Wc + (size_t)t * 8) = o;
  } else {
    __shared__ float r1[256], r3[256], r5[256];
    const int tp = threadIdx.x;  // 256
    float s1 = 0.f, s3 = 0.f, s5 = 0.f;
    for (int a = tp; a < AA; a += 256) {
      const float w = W3[a], u = W4[2 * AA + a];
      const float w2 = w * w;
      s1 += u * w; s3 += u * w * w2; s5 += u * w * w2 * w2;
    }
    r1[tp] = s1; r3[tp] = s3; r5[tp] = s5;
    __syncthreads();
    for (int off = 128; off > 0; off >>= 1) {
      if (tp < off) { r1[tp] += r1[tp + off]; r3[tp] += r3[tp + off]; r5[tp] += r5[tp + off]; }
      __syncthreads();
    }
    if (tp == 0) { C[0] = r1[0]; C[1] = -r3[0] / 3.f; C[2] = r5[0] * (2.f / 15.f); }
  }
}

// ---- big fused GEMM: e1[row] = sum_a V[a]*tanh( X[row,:] . W[a,:] ) --------
// HIGH-ILP / LOW-TLP variant: 512 threads, __launch_bounds__(512,2) ->
// 256-VGPR budget, 1 block/CU (grid 256), each block persistent over 4
// row-tiles of 64. B is the SAME for every row-tile (bug fixed from r14:
// no per-tile bp offset -- the K-loop itself walks the whole 1MB Wc).
// Per tile: 16 K-steps (BK=64), FULLY UNROLLED static schedule over 3 LDS
// A-buffers + 2 B register sets:
//   step j: AWR A(j+2)->buf[(j+2)%3] (== buffer read at j-1: barrier-safe),
//           ALOAD A(j+3), BLOAD B(j+1)->regset[(j+1)&1],
//           COMPUTE(buf[j%3], regset[j&1]), lgkmcnt-only barrier.
// Every VMEM consumer has >= 1 full step (~2000cyc) slack; barriers order
// only 16KB of ds_writes issued a step earlier. No vmcnt at barriers; no
// setprio (m190). acc 64 + B dbuf 64 + A held 16 + addr ~= 175 VGPR.
__global__ __launch_bounds__(512, 2)
void e1_gemm(const float* __restrict__ enc, const float* __restrict__ h0,
             const unsigned short* __restrict__ W1c, const unsigned short* __restrict__ W5c,
             const float* __restrict__ W4, const float* __restrict__ W8,
             float* __restrict__ e1s, float* __restrict__ e1t) {
  const int wg   = blockIdx.x;        // 0..255; 256 rows each
  const int tid  = threadIdx.x;       // 512
  const int lane = tid & 63;
  const int colg = tid >> 6;          // 0..7 (64-col group)
  const int l15  = lane & 15;
  const int lg   = lane >> 4;         // 0..3

  const bool is_enc = wg < 128;
  const float* __restrict__ Xg = is_enc ? enc : h0;
  const unsigned short* __restrict__ Wc = is_enc ? W1c : W5c;
  const float* __restrict__ Vg = is_enc ? W4 : W8;
  const int row0 = (is_enc ? wg : wg - 128) * 256;

  __shared__ char lds_raw[LRED + 2048];
  float* lred = (float*)(lds_raw + LRED);   // [8][64]

  // ---- A staging geometry (r13-verified, 0 conflicts) ----------------------
  const int arow = tid >> 3;                     // 0..63
  const int aq   = tid & 7;                      // 0..7 (4 floats each)
  const int slotS = (aq >> 1) ^ ((arow >> 1) & 3);
  const int aDst = arow * 64 + slotS * 16 + (aq & 1) * 8;
  const int aRd = l15 * 64 + ((lg ^ ((l15 >> 1) & 3)) << 4);

  // B: same pointer for all tiles; K-loop covers the full 1MB Wc.
  const char* bp = (const char*)Wc + colg * 4096 + lane * 16;

  float vvv[4];
#pragma unroll
  for (int cf = 0; cf < 4; ++cf) vvv[cf] = Vg[colg * 64 + cf * 16 + l15];

#define ALOADN(k_) do {                                                       \
    an0 = *(const f4*)(ap + (k_) * 64);                                       \
    an1 = *(const f4*)(ap + (k_) * 64 + 32);                                  \
  } while (0)
#define ALOADM(k_) do {                                                       \
    am0 = *(const f4*)(ap + (k_) * 64);                                       \
    am1 = *(const f4*)(ap + (k_) * 64 + 32);                                  \
  } while (0)
#define AWRX(bo_, x0_, x1_) do {                                              \
    uint2 o0_, o1_;                                                           \
    o0_.x = f2bu(x0_[0]) | (f2bu(x0_[1]) << 16);                              \
    o0_.y = f2bu(x0_[2]) | (f2bu(x0_[3]) << 16);                              \
    o1_.x = f2bu(x1_[0]) | (f2bu(x1_[1]) << 16);                              \
    o1_.y = f2bu(x1_[2]) | (f2bu(x1_[3]) << 16);                              \
    *(uint2*)(lds_raw + (bo_) + aDst) = o0_;                                  \
    *(uint2*)(lds_raw + (bo_) + 4096 + aDst) = o1_;                           \
  } while (0)
#define BLOAD(dst_, kb_) do {                                                 \
    const char* b_ = bp + (size_t)(kb_) * 65536;                              \
    dst_[0] = *(const short8*)(b_);                                           \
    dst_[1] = *(const short8*)(b_ + 1024);                                    \
    dst_[2] = *(const short8*)(b_ + 2048);                                    \
    dst_[3] = *(const short8*)(b_ + 3072);                                    \
    dst_[4] = *(const short8*)(b_ + 32768);                                   \
    dst_[5] = *(const short8*)(b_ + 32768 + 1024);                            \
    dst_[6] = *(const short8*)(b_ + 32768 + 2048);                            \
    dst_[7] = *(const short8*)(b_ + 32768 + 3072);                            \
  } while (0)
#define COMPUTE(bo_, bfr_) do {                                               \
    const char* base_ = lds_raw + (bo_);                                      \
    _Pragma("unroll")                                                         \
    for (int ks_ = 0; ks_ < 2; ++ks_) {                                       \
      _Pragma("unroll")                                                       \
      for (int rt = 0; rt < 4; ++rt) {                                        \
        short8 af_ = *(const short8*)(base_ + ks_ * 4096 + aRd + rt * 1024);  \
        _Pragma("unroll")                                                     \
        for (int cf = 0; cf < 4; ++cf)                                        \
          acc[rt][cf] = __builtin_amdgcn_mfma_f32_16x16x32_bf16(              \
              af_, bfr_[ks_ * 4 + cf], acc[rt][cf], 0, 0, 0);                 \
      }                                                                       \
    }                                                                         \
  } while (0)
#define SYNCA() do {                                                          \
    __builtin_amdgcn_sched_barrier(0);                                        \
    asm volatile("s_waitcnt lgkmcnt(0)" ::: "memory");                        \
    __builtin_amdgcn_s_barrier();                                             \
    __builtin_amdgcn_sched_barrier(0);                                        \
  } while (0)
#define STEPF(J_, BW_, BC_, SW_, SC_) do {                                    \
    AWRX(BW_, an0, an1);                                                      \
    ALOADN((J_) + 3);                                                         \
    BLOAD(SW_, (J_) + 1);                                                     \
    COMPUTE(BC_, SC_);                                                        \
    SYNCA();                                                                  \
  } while (0)

#pragma unroll 1
  for (int tile = 0; tile < 4; ++tile) {
    const float* ap = Xg + (size_t)(row0 + tile * 64 + arow) * HH + aq * 4;

    f4 acc[4][4];
#pragma unroll
    for (int i = 0; i < 4; ++i)
#pragma unroll
      for (int j = 0; j < 4; ++j) acc[i][j] = (f4){0.f, 0.f, 0.f, 0.f};

    f4 an0, an1, am0, am1;
    short8 bfa[8], bfb[8];

    // ---- prologue: A0->buf0, A1->buf1, A2 held, B0->bfa ---------------------
    ALOADN(0); ALOADM(1);
    AWRX(AB0, an0, an1);
    AWRX(AB1, am0, am1);
    ALOADN(2);
    BLOAD(bfa, 0);
    SYNCA();

    // ---- 16 steps, fully unrolled static schedule ---------------------------
    STEPF(0,  AB2, AB0, bfb, bfa);
    STEPF(1,  AB0, AB1, bfa, bfb);
    STEPF(2,  AB1, AB2, bfb, bfa);
    STEPF(3,  AB2, AB0, bfa, bfb);
    STEPF(4,  AB0, AB1, bfb, bfa);
    STEPF(5,  AB1, AB2, bfa, bfb);
    STEPF(6,  AB2, AB0, bfb, bfa);
    STEPF(7,  AB0, AB1, bfa, bfb);
    STEPF(8,  AB1, AB2, bfb, bfa);
    STEPF(9,  AB2, AB0, bfa, bfb);
    STEPF(10, AB0, AB1, bfb, bfa);
    STEPF(11, AB1, AB2, bfa, bfb);
    STEPF(12, AB2, AB0, bfb, bfa);
    // j=13: A15 (held) -> buf0; no ALOAD
    AWRX(AB0, an0, an1); BLOAD(bfa, 14); COMPUTE(AB1, bfb); SYNCA();
    // j=14
    BLOAD(bfb, 15); COMPUTE(AB2, bfa); SYNCA();
    // j=15
    COMPUTE(AB0, bfb);

    // ---- per-tile epilogue: tanh, V-weight, 16-lane reduce, cross-colg ------
#pragma unroll
    for (int rt = 0; rt < 4; ++rt) {
      float ps[4] = {0.f, 0.f, 0.f, 0.f};
#pragma unroll
      for (int cf = 0; cf < 4; ++cf) {
        const float w = vvv[cf];
#pragma unroll
        for (int r = 0; r < 4; ++r) ps[r] += w * tanh_fast(acc[rt][cf][r]);
      }
#pragma unroll
      for (int r = 0; r < 4; ++r) {
#pragma unroll
        for (int off = 1; off < 16; off <<= 1) ps[r] += __shfl_xor(ps[r], off);
      }
      if (l15 == 0) {
#pragma unroll
        for (int r = 0; r < 4; ++r)
          lred[colg * 64 + rt * 16 + lg * 4 + r] = ps[r];
      }
    }
    __syncthreads();
    if (tid < 64) {
      float s = 0.f;
#pragma unroll
      for (int c = 0; c < 8; ++c) s += lred[c * 64 + tid];
      const int gr = row0 + tile * 64 + tid;
      const int q = gr >> 5;            // s or t index
      const int b = gr & 31;
      if (is_enc) e1s[b * SS + q] = s;
      else        e1t[b * TN + q] = s;
    }
    __syncthreads();   // lred reads done before next tile reuses LDS/barriers
  }
#undef ALOADN
#undef ALOADM
#undef AWRX
#undef BLOAD
#undef COMPUTE
#undef SYNCA
#undef STEPF
}

// ---------------- merged softmaxes: blocks 0..31 = s-side, 32..63 = t-side --
__global__ void softmax_both(const float* __restrict__ e1s, const float* __restrict__ e1t,
                             const float* __restrict__ ax, const float* __restrict__ C,
                             float* __restrict__ axi, float* __restrict__ ati,
                             float* __restrict__ axnew) {
  const int tid = threadIdx.x;  // 256
  __shared__ float red[256];
  if (blockIdx.x < BB) {
    const int b = blockIdx.x;
    const float c0 = C[0], c1 = C[1], c2 = C[2];
    float loc[4], xv[4];
    float m = -1e30f;
#pragma unroll
    for (int i = 0; i < 4; ++i) {
      const int s = i * 256 + tid;
      const float x = ax[b * SS + s];
      const float x2 = x * x;
      xv[i] = x;
      loc[i] = e1s[b * SS + s] + x * (c0 + x2 * (c1 + x2 * c2));
      m = fmaxf(m, loc[i]);
    }
    red[tid] = m; __syncthreads();
    for (int off = 128; off > 0; off >>= 1) {
      if (tid < off) red[tid] = fmaxf(red[tid], red[tid + off]);
      __syncthreads();
    }
    m = red[0]; __syncthreads();
    float sum = 0.f;
#pragma unroll
    for (int i = 0; i < 4; ++i) { loc[i] = __expf(loc[i] - m); sum += loc[i]; }
    red[tid] = sum; __syncthreads();
    for (int off = 128; off > 0; off >>= 1) {
      if (tid < off) red[tid] += red[tid + off];
      __syncthreads();
    }
    const float inv = 1.f / red[0];
#pragma unroll
    for (int i = 0; i < 4; ++i) {
      const int s = i * 256 + tid;
      const float a_ = loc[i] * inv;
      axi[b * SS + s] = a_;
      axnew[b * SS + s] = xv[i] + a_;
    }
  } else {
    const int b = blockIdx.x - BB;
    float loc[4];
    float m = -1e30f;
#pragma unroll
    for (int i = 0; i < 4; ++i) { loc[i] = e1t[b * TN + i * 256 + tid]; m = fmaxf(m, loc[i]); }
    red[tid] = m; __syncthreads();
    for (int off = 128; off > 0; off >>= 1) {
      if (tid < off) red[tid] = fmaxf(red[tid], red[tid + off]);
      __syncthreads();
    }
    m = red[0]; __syncthreads();
    float sum = 0.f;
#pragma unroll
    for (int i = 0; i < 4; ++i) { loc[i] = __expf(loc[i] - m); sum += loc[i]; }
    red[tid] = sum; __syncthreads();
    for (int off = 128; off > 0; off >>= 1) {
      if (tid < off) red[tid] += red[tid + off];
      __syncthreads();
    }
    const float inv = 1.f / red[0];
#pragma unroll
    for (int i = 0; i < 4; ++i) ati[b * TN + (i * 256 + tid)] = loc[i] * inv;
  }
}

// ---------------- merged chunked weighted sums (x and t streams) ------------
__global__ void wpart2(const float* __restrict__ enc, const float* __restrict__ h0,
                       const float* __restrict__ axi, const float* __restrict__ ati,
                       float* __restrict__ partx, float* __restrict__ partt) {
  const int gb = blockIdx.x;                 // 0..511
  const bool isx = gb < BB * NCH;
  const float* __restrict__ X = isx ? enc : h0;
  const float* __restrict__ w = isx ? axi : ati;
  float* __restrict__ part = isx ? partx : partt;
  const int idx = isx ? gb : gb - BB * NCH;
  const int b = idx / NCH, ch = idx % NCH;
  const int tid = threadIdx.x;  // 256, each handles 4 h
  __shared__ float ws[SS / NCH];
  if (tid < SS / NCH) ws[tid] = w[b * SS + ch * (SS / NCH) + tid];
  __syncthreads();
  f4 acc = (f4){0.f, 0.f, 0.f, 0.f};
  const float* base = X + ((size_t)(ch * (SS / NCH)) * BB + b) * HH + tid * 4;
#pragma unroll 4
  for (int i = 0; i < SS / NCH; ++i) {
    f4 x = *(const f4*)(base + (size_t)i * BB * HH);
    acc += ws[i] * x;
  }
  *(f4*)&part[((size_t)(b * NCH + ch)) * HH + tid * 4] = acc;
}

__global__ void wreduce2(const float* __restrict__ partx, const float* __restrict__ partt,
                         float* __restrict__ cxi, float* __restrict__ cti) {
  const int idx = blockIdx.x * 256 + threadIdx.x;  // over 2*B*H
  const bool isx = idx < BB * HH;
  const float* __restrict__ part = isx ? partx : partt;
  float* __restrict__ outp = isx ? cxi : cti;
  const int j = isx ? idx : idx - BB * HH;
  const int b = j / HH, h = j % HH;
  float s = 0.f;
#pragma unroll
  for (int ch = 0; ch < NCH; ++ch) s += part[((size_t)(b * NCH + ch)) * HH + h];
  outp[j] = s;
}

// ---- ci[b,h] = z*tanh(cxi.W9[h,:]) + (1-z)*tanh(cti.W10[h,:]), z fused ----
__global__ void ci_kernel(const float* __restrict__ cxi, const float* __restrict__ cti,
                          const float* __restrict__ W9, const float* __restrict__ W10,
                          const float* __restrict__ W11, float* __restrict__ out_ci) {
  const int b = blockIdx.x >> 2, hb = blockIdx.x & 3, tid = threadIdx.x;
  const int h = hb * 256 + tid;
  __shared__ float cx[HH], ct[HH];
  __shared__ float zred[4];
  for (int i = tid; i < HH; i += 256) { cx[i] = cxi[b * HH + i]; ct[i] = cti[b * HH + i]; }
  __syncthreads();
  float zs = 0.f;
  for (int i = tid; i < HH; i += 256) zs += cx[i] * W11[i] + ct[i] * W11[HH + i];
  for (int off = 32; off > 0; off >>= 1) zs += __shfl_down(zs, off);
  if ((tid & 63) == 0) zred[tid >> 6] = zs;
  __syncthreads();
  const float zt = zred[0] + zred[1] + zred[2] + zred[3];
  const float z = 1.f / (1.f + __expf(-zt));

  const float* __restrict__ w9r  = W9  + (size_t)h * HH;
  const float* __restrict__ w10r = W10 + (size_t)h * HH;
  float gx = 0.f, gt = 0.f;
  for (int k = 0; k < HH; k += 4) {
    f4 a = *(const f4*)(w9r + k);
    f4 c = *(const f4*)(w10r + k);
    gx += cx[k] * a[0] + cx[k + 1] * a[1] + cx[k + 2] * a[2] + cx[k + 3] * a[3];
    gt += ct[k] * c[0] + ct[k + 1] * c[1] + ct[k + 2] * c[2] + ct[k + 3] * c[3];
  }
  out_ci[b * HH + h] = z * tanhf(gx) + (1.f - z) * tanhf(gt);
}

extern "C" void kernel_launch(void* const* d_in, const int* in_sizes, int n_in,
                              void* d_out, int out_size, void* d_ws, size_t ws_size,
                              hipStream_t stream) {
  const float* enc = (const float*)d_in[1];
  const float* h0  = (const float*)d_in[2];
  const float* ax  = (const float*)d_in[3];
  const float* W1  = (const float*)d_in[4];
  const float* W3  = (const float*)d_in[6];
  const float* W4  = (const float*)d_in[7];
  const float* W5  = (const float*)d_in[8];
  const float* W8  = (const float*)d_in[11];
  const float* W9  = (const float*)d_in[12];
  const float* W10 = (const float*)d_in[13];
  const float* W11 = (const float*)d_in[14];
  float* out = (float*)d_out;  // [0:B*H) ci, [B*H : 2*B*H) ax_new

  // Workspace layout (floats). W1c/W5c each 512*1024 bf16 = 262144 floats (1MB).
  // partx/partt ALIAS the Wc regions: Wc dead after e1_gemm; prep_all recreates
  // Wc at the start of every call (deterministic across graph replays).
  float* w = (float*)d_ws;
  unsigned short* W1c = (unsigned short*)w;            // floats [0, 262144)
  unsigned short* W5c = (unsigned short*)(w + 262144); // floats [262144, 524288)
  float* partx = w;                  // aliases W1c
  float* partt = w + 262144;         // aliases W5c
  float* e1s   = w + 524288;         // 32768 (transposed [b][s])
  float* e1t   = w + 557056;         // 32768 (transposed [b][t])
  float* axi   = w + 589824;         // 32768
  float* ati   = w + 622592;         // 32768
  float* cxi   = w + 655360;         // 32768
  float* cti   = w + 688128;         // 32768
  float* Cpoly = w + 720896;         // 16   (end: ~2.88 MB)

  prep_all<<<513, 256, 0, stream>>>(W1, W5, W3, W4, W1c, W5c, Cpoly);
  e1_gemm<<<256, 512, 0, stream>>>(enc, h0, W1c, W5c, W4, W8, e1s, e1t);
  softmax_both<<<2 * BB, 256, 0, stream>>>(e1s, e1t, ax, Cpoly, axi, ati, out + BB * HH);
  wpart2<<<2 * BB * NCH, 256, 0, stream>>>(enc, h0, axi, ati, partx, partt);
  wreduce2<<<2 * BB * HH / 256, 256, 0, stream>>>(partx, partt, cxi, cti);
  ci_kernel<<<BB * 4, 256, 0, stream>>>(cxi, cti, W9, W10, W11, out);
}

// Round 16
// 216.353 us; speedup vs baseline: 1.5671x; 1.5671x over previous
//
#include <hip/hip_runtime.h>
#include <hip/hip_bf16.h>

#define HH 1024
#define AA 512
#define BB 32
#define SS 1024
#define TN 1024
#define M_ENC (SS*BB)
#define M_TOT ((SS+TN)*BB)
#define NCH 8

// e1_gemm LDS: A buffer = 2 halves x (64 rows x 64B) = 8KB; double-buffered.
#define ABUF 8192

typedef __attribute__((ext_vector_type(8))) short short8;
typedef __attribute__((ext_vector_type(4))) float f4;

union bfu { __hip_bfloat16 h; unsigned short u; };
__device__ __forceinline__ unsigned int f2bu(float x) {
  bfu t; t.h = __float2bfloat16(x); return (unsigned int)t.u;
}
__device__ __forceinline__ unsigned short f2b(float x) {
  bfu t; t.h = __float2bfloat16(x); return t.u;
}
__device__ __forceinline__ float tanh_fast(float x) {
  float e = __expf(2.f * x);
  return 1.f - 2.f / (e + 1.f);
}

// ---- merged prep: W1/W5 -> bf16 fragment-order repack + poly coefficients --
// blocks 0..255: W1; 256..511: W5; block 512: poly.
// Wc layout: frag id t = ((kb*32 + rg)*64 + lane), 8 bf16 per frag,
// fragment holds W[rg*16 + (lane&15)][kb*32 + (lane>>4)*8 + j].
__global__ void prep_all(const float* __restrict__ W1, const float* __restrict__ W5,
                         const float* __restrict__ W3, const float* __restrict__ W4,
                         unsigned short* __restrict__ W1c, unsigned short* __restrict__ W5c,
                         float* __restrict__ C) {
  if (blockIdx.x < 512) {
    const float* __restrict__ W = (blockIdx.x < 256) ? W1 : W5;
    unsigned short* __restrict__ Wc = (blockIdx.x < 256) ? W1c : W5c;
    const int t = (blockIdx.x & 255) * 256 + threadIdx.x;   // 0..65535
    const int lane = t & 63;
    const int rg = (t >> 6) & 31;
    const int kb = t >> 11;
    const int row = rg * 16 + (lane & 15);
    const int k = kb * 32 + ((lane >> 4) << 3);
    const float* src = W + (size_t)row * HH + k;
    f4 v0 = *(const f4*)(src);
    f4 v1 = *(const f4*)(src + 4);
    short8 o;
    o[0] = f2b(v0[0]); o[1] = f2b(v0[1]); o[2] = f2b(v0[2]); o[3] = f2b(v0[3]);
    o[4] = f2b(v1[0]); o[5] = f2b(v1[1]); o[6] = f2b(v1[2]); o[7] = f2b(v1[3]);
    *(short8*)(Wc + (size_t)t * 8) = o;
  } else {
    __shared__ float r1[256], r3[256], r5[256];
    const int tp = threadIdx.x;  // 256
    float s1 = 0.f, s3 = 0.f, s5 = 0.f;
    for (int a = tp; a < AA; a += 256) {
      const float w = W3[a], u = W4[2 * AA + a];
      const float w2 = w * w;
      s1 += u * w; s3 += u * w * w2; s5 += u * w * w2 * w2;
    }
    r1[tp] = s1; r3[tp] = s3; r5[tp] = s5;
    __syncthreads();
    for (int off = 128; off > 0; off >>= 1) {
      if (tp < off) { r1[tp] += r1[tp + off]; r3[tp] += r3[tp + off]; r5[tp] += r5[tp + off]; }
      __syncthreads();
    }
    if (tp == 0) { C[0] = r1[0]; C[1] = -r3[0] / 3.f; C[2] = r5[0] * (2.f / 15.f); }
  }
}

// ---- big fused GEMM: e1[row] = sum_a V[a]*tanh( X[row,:] . W[a,:] ) --------
// r13 skeleton (best measured: 136us): BM=64, 512 threads = 8 waves (1x8
// col-groups), wave tile 64x64, acc[4][4], BK=64 (16 K-steps), 2 blocks/CU,
// A reg-staged one step ahead (0-conflict XOR layout), lgkmcnt-only barrier.
// NEW (r16): B prefetched ONE STEP AHEAD into the SAME bfr registers (WAR
// recycling, zero extra VGPR), split in halves interleaved with the MFMA
// clusters: after ks=0 consumes bfr[0..3], issue BH0(j+1) into them; after
// ks=1 consumes bfr[4..7], issue BH1(j+1). Each half gets ~400-600cyc of
// cover (rest of compute + barrier + next step's AWR/ds_read) instead of
// ~100cyc -> removes the ~200cyc/step exposed L2 latency on B.
__global__ __launch_bounds__(512, 4)
void e1_gemm(const float* __restrict__ enc, const float* __restrict__ h0,
             const unsigned short* __restrict__ W1c, const unsigned short* __restrict__ W5c,
             const float* __restrict__ W4, const float* __restrict__ W8,
             float* __restrict__ e1s, float* __restrict__ e1t) {
  const int wg   = blockIdx.x;        // 1024 blocks, 64 rows each
  const int tid  = threadIdx.x;       // 512
  const int lane = tid & 63;
  const int colg = tid >> 6;          // 0..7 (64-col group)
  const int l15  = lane & 15;
  const int lg   = lane >> 4;         // 0..3

  const bool is_enc = (wg * 64) < M_ENC;
  const float* __restrict__ Xg = is_enc ? enc : h0;
  const unsigned short* __restrict__ Wc = is_enc ? W1c : W5c;
  const float* __restrict__ Vg = is_enc ? W4 : W8;
  const int row0 = is_enc ? wg * 64 : wg * 64 - M_ENC;

  __shared__ char lds_raw[2 * ABUF];
  float* lred = (float*)lds_raw;      // [8][64] floats, epilogue only

  f4 acc[4][4];
#pragma unroll
  for (int i = 0; i < 4; ++i)
#pragma unroll
    for (int j = 0; j < 4; ++j) acc[i][j] = (f4){0.f, 0.f, 0.f, 0.f};

  // ---- A staging: thread -> (row, quad); 2 f4 loads + 2 8B ds_writes -------
  const int arow = tid >> 3;                     // 0..63
  const int aq   = tid & 7;                      // 0..7 (4 floats each)
  const float* ap = Xg + (size_t)(row0 + arow) * HH + aq * 4;
  const int slotS = (aq >> 1) ^ ((arow >> 1) & 3);
  const int aDst = arow * 64 + slotS * 16 + (aq & 1) * 8;

  // ---- A fragment read base (r9-r13 verified swizzle); + ks*4096 + rt*1024 --
  const int aRd = l15 * 64 + ((lg ^ ((l15 >> 1) & 3)) << 4);

  // ---- B: per-thread global base; step kb at +kb*64KB ------------------------
  const char* bp = (const char*)Wc + colg * 4096 + lane * 16;

  f4 an0, an1;                                   // A regs for NEXT step
  short8 bfr[8];                                 // B frags, WAR-recycled

#define ALOAD(k_) do {                                                        \
    an0 = *(const f4*)(ap + (k_) * 64);                                       \
    an1 = *(const f4*)(ap + (k_) * 64 + 32);                                  \
  } while (0)

#define AWR(bo_) do {                                                         \
    uint2 o0_, o1_;                                                           \
    o0_.x = f2bu(an0[0]) | (f2bu(an0[1]) << 16);                              \
    o0_.y = f2bu(an0[2]) | (f2bu(an0[3]) << 16);                              \
    o1_.x = f2bu(an1[0]) | (f2bu(an1[1]) << 16);                              \
    o1_.y = f2bu(an1[2]) | (f2bu(an1[3]) << 16);                              \
    *(uint2*)(lds_raw + (bo_) + aDst) = o0_;                                  \
    *(uint2*)(lds_raw + (bo_) + 4096 + aDst) = o1_;                           \
  } while (0)

#define BH0(kb_) do {                                                         \
    const char* b_ = bp + (size_t)(kb_) * 65536;                              \
    bfr[0] = *(const short8*)(b_);                                            \
    bfr[1] = *(const short8*)(b_ + 1024);                                     \
    bfr[2] = *(const short8*)(b_ + 2048);                                     \
    bfr[3] = *(const short8*)(b_ + 3072);                                     \
  } while (0)

#define BH1(kb_) do {                                                         \
    const char* b_ = bp + (size_t)(kb_) * 65536 + 32768;                      \
    bfr[4] = *(const short8*)(b_);                                            \
    bfr[5] = *(const short8*)(b_ + 1024);                                     \
    bfr[6] = *(const short8*)(b_ + 2048);                                     \
    bfr[7] = *(const short8*)(b_ + 3072);                                     \
  } while (0)

#define COMP0(bo_) do {                                                       \
    const char* base_ = lds_raw + (bo_);                                      \
    __builtin_amdgcn_s_setprio(1);                                            \
    _Pragma("unroll")                                                         \
    for (int rt = 0; rt < 4; ++rt) {                                          \
      short8 af_ = *(const short8*)(base_ + aRd + rt * 1024);                 \
      _Pragma("unroll")                                                       \
      for (int cf = 0; cf < 4; ++cf)                                          \
        acc[rt][cf] = __builtin_amdgcn_mfma_f32_16x16x32_bf16(                \
            af_, bfr[cf], acc[rt][cf], 0, 0, 0);                              \
    }                                                                         \
    __builtin_amdgcn_s_setprio(0);                                            \
  } while (0)

#define COMP1(bo_) do {                                                       \
    const char* base_ = lds_raw + (bo_) + 4096;                               \
    __builtin_amdgcn_s_setprio(1);                                            \
    _Pragma("unroll")                                                         \
    for (int rt = 0; rt < 4; ++rt) {                                          \
      short8 af_ = *(const short8*)(base_ + aRd + rt * 1024);                 \
      _Pragma("unroll")                                                       \
      for (int cf = 0; cf < 4; ++cf)                                          \
        acc[rt][cf] = __builtin_amdgcn_mfma_f32_16x16x32_bf16(                \
            af_, bfr[4 + cf], acc[rt][cf], 0, 0, 0);                          \
    }                                                                         \
    __builtin_amdgcn_s_setprio(0);                                            \
  } while (0)

// barrier ordering ONLY LDS traffic; A/B global loads may stay in flight
#define SYNCA() do {                                                          \
    __builtin_amdgcn_sched_barrier(0);                                        \
    asm volatile("s_waitcnt lgkmcnt(0)" ::: "memory");                        \
    __builtin_amdgcn_s_barrier();                                             \
    __builtin_amdgcn_sched_barrier(0);                                        \
  } while (0)

  // ---- prologue: A(0)->buf0, A(1) held, B(0)->bfr ---------------------------
  ALOAD(0);
  AWR(0);                 // waits its own A(0) loads (auto vmcnt)
  ALOAD(1);               // A(1) in flight across the barrier
  BH0(0); BH1(0);         // B(0) in flight across the barrier
  SYNCA();                // publish buf0

  // ---- steps 0..13, unrolled x2: step j computes (A(j),B(j)) on buf(j%2),
  //      writes A(j+1) to the other buf, prefetches A(j+2) and B(j+1) --------
#pragma unroll 1
  for (int it = 0; it < 7; ++it) {
    // even step 2it
    AWR(ABUF); ALOAD(2 * it + 2);
    COMP0(0); BH0(2 * it + 1);
    COMP1(0); BH1(2 * it + 1);
    SYNCA();
    // odd step 2it+1
    AWR(0); ALOAD(2 * it + 3);
    COMP0(ABUF); BH0(2 * it + 2);
    COMP1(ABUF); BH1(2 * it + 2);
    SYNCA();
  }
  // step 14: A(15) (held) -> buf1; compute (A14,B14) on buf0; prefetch B15
  AWR(ABUF);
  COMP0(0); BH0(15);
  COMP1(0); BH1(15);
  SYNCA();
  // step 15: compute (A15,B15) on buf1
  COMP0(ABUF);
  COMP1(ABUF);
#undef ALOAD
#undef AWR
#undef BH0
#undef BH1
#undef COMP0
#undef COMP1
#undef SYNCA

  // epilogue: tanh, weight by V, reduce 16 col-lanes, then across col-groups
  float vvv[4];
#pragma unroll
  for (int cf = 0; cf < 4; ++cf) vvv[cf] = Vg[colg * 64 + cf * 16 + l15];

  __syncthreads();   // A buffers dead; lred aliases buf0
#pragma unroll
  for (int rt = 0; rt < 4; ++rt) {
    float ps[4] = {0.f, 0.f, 0.f, 0.f};
#pragma unroll
    for (int cf = 0; cf < 4; ++cf) {
      const float w = vvv[cf];
#pragma unroll
      for (int r = 0; r < 4; ++r) ps[r] += w * tanh_fast(acc[rt][cf][r]);
    }
#pragma unroll
    for (int r = 0; r < 4; ++r) {
#pragma unroll
      for (int off = 1; off < 16; off <<= 1) ps[r] += __shfl_xor(ps[r], off);
    }
    if (l15 == 0) {
#pragma unroll
      for (int r = 0; r < 4; ++r)
        lred[colg * 64 + rt * 16 + lg * 4 + r] = ps[r];
    }
  }
  __syncthreads();
  if (tid < 64) {
    float s = 0.f;
#pragma unroll
    for (int c = 0; c < 8; ++c) s += lred[c * 64 + tid];
    const int gr = row0 + tid;
    const int q = gr >> 5;            // s or t index
    const int b = gr & 31;
    if (is_enc) e1s[b * SS + q] = s;
    else        e1t[b * TN + q] = s;
  }
}

// ---------------- merged softmaxes: blocks 0..31 = s-side, 32..63 = t-side --
__global__ void softmax_both(const float* __restrict__ e1s, const float* __restrict__ e1t,
                             const float* __restrict__ ax, const float* __restrict__ C,
                             float* __restrict__ axi, float* __restrict__ ati,
                             float* __restrict__ axnew) {
  const int tid = threadIdx.x;  // 256
  __shared__ float red[256];
  if (blockIdx.x < BB) {
    const int b = blockIdx.x;
    const float c0 = C[0], c1 = C[1], c2 = C[2];
    float loc[4], xv[4];
    float m = -1e30f;
#pragma unroll
    for (int i = 0; i < 4; ++i) {
      const int s = i * 256 + tid;
      const float x = ax[b * SS + s];
      const float x2 = x * x;
      xv[i] = x;
      loc[i] = e1s[b * SS + s] + x * (c0 + x2 * (c1 + x2 * c2));
      m = fmaxf(m, loc[i]);
    }
    red[tid] = m; __syncthreads();
    for (int off = 128; off > 0; off >>= 1) {
      if (tid < off) red[tid] = fmaxf(red[tid], red[tid + off]);
      __syncthreads();
    }
    m = red[0]; __syncthreads();
    float sum = 0.f;
#pragma unroll
    for (int i = 0; i < 4; ++i) { loc[i] = __expf(loc[i] - m); sum += loc[i]; }
    red[tid] = sum; __syncthreads();
    for (int off = 128; off > 0; off >>= 1) {
      if (tid < off) red[tid] += red[tid + off];
      __syncthreads();
    }
    const float inv = 1.f / red[0];
#pragma unroll
    for (int i = 0; i < 4; ++i) {
      const int s = i * 256 + tid;
      const float a_ = loc[i] * inv;
      axi[b * SS + s] = a_;
      axnew[b * SS + s] = xv[i] + a_;
    }
  } else {
    const int b = blockIdx.x - BB;
    float loc[4];
    float m = -1e30f;
#pragma unroll
    for (int i = 0; i < 4; ++i) { loc[i] = e1t[b * TN + i * 256 + tid]; m = fmaxf(m, loc[i]); }
    red[tid] = m; __syncthreads();
    for (int off = 128; off > 0; off >>= 1) {
      if (tid < off) red[tid] = fmaxf(red[tid], red[tid + off]);
      __syncthreads();
    }
    m = red[0]; __syncthreads();
    float sum = 0.f;
#pragma unroll
    for (int i = 0; i < 4; ++i) { loc[i] = __expf(loc[i] - m); sum += loc[i]; }
    red[tid] = sum; __syncthreads();
    for (int off = 128; off > 0; off >>= 1) {
      if (tid < off) red[tid] += red[tid + off];
      __syncthreads();
    }
    const float inv = 1.f / red[0];
#pragma unroll
    for (int i = 0; i < 4; ++i) ati[b * TN + (i * 256 + tid)] = loc[i] * inv;
  }
}

// ---------------- merged chunked weighted sums (x and t streams) ------------
__global__ void wpart2(const float* __restrict__ enc, const float* __restrict__ h0,
                       const float* __restrict__ axi, const float* __restrict__ ati,
                       float* __restrict__ partx, float* __restrict__ partt) {
  const int gb = blockIdx.x;                 // 0..511
  const bool isx = gb < BB * NCH;
  const float* __restrict__ X = isx ? enc : h0;
  const float* __restrict__ w = isx ? axi : ati;
  float* __restrict__ part = isx ? partx : partt;
  const int idx = isx ? gb : gb - BB * NCH;
  const int b = idx / NCH, ch = idx % NCH;
  const int tid = threadIdx.x;  // 256, each handles 4 h
  __shared__ float ws[SS / NCH];
  if (tid < SS / NCH) ws[tid] = w[b * SS + ch * (SS / NCH) + tid];
  __syncthreads();
  f4 acc = (f4){0.f, 0.f, 0.f, 0.f};
  const float* base = X + ((size_t)(ch * (SS / NCH)) * BB + b) * HH + tid * 4;
#pragma unroll 4
  for (int i = 0; i < SS / NCH; ++i) {
    f4 x = *(const f4*)(base + (size_t)i * BB * HH);
    acc += ws[i] * x;
  }
  *(f4*)&part[((size_t)(b * NCH + ch)) * HH + tid * 4] = acc;
}

__global__ void wreduce2(const float* __restrict__ partx, const float* __restrict__ partt,
                         float* __restrict__ cxi, float* __restrict__ cti) {
  const int idx = blockIdx.x * 256 + threadIdx.x;  // over 2*B*H
  const bool isx = idx < BB * HH;
  const float* __restrict__ part = isx ? partx : partt;
  float* __restrict__ outp = isx ? cxi : cti;
  const int j = isx ? idx : idx - BB * HH;
  const int b = j / HH, h = j % HH;
  float s = 0.f;
#pragma unroll
  for (int ch = 0; ch < NCH; ++ch) s += part[((size_t)(b * NCH + ch)) * HH + h];
  outp[j] = s;
}

// ---- ci[b,h] = z*tanh(cxi.W9[h,:]) + (1-z)*tanh(cti.W10[h,:]), z fused ----
__global__ void ci_kernel(const float* __restrict__ cxi, const float* __restrict__ cti,
                          const float* __restrict__ W9, const float* __restrict__ W10,
                          const float* __restrict__ W11, float* __restrict__ out_ci) {
  const int b = blockIdx.x >> 2, hb = blockIdx.x & 3, tid = threadIdx.x;
  const int h = hb * 256 + tid;
  __shared__ float cx[HH], ct[HH];
  __shared__ float zred[4];
  for (int i = tid; i < HH; i += 256) { cx[i] = cxi[b * HH + i]; ct[i] = cti[b * HH + i]; }
  __syncthreads();
  float zs = 0.f;
  for (int i = tid; i < HH; i += 256) zs += cx[i] * W11[i] + ct[i] * W11[HH + i];
  for (int off = 32; off > 0; off >>= 1) zs += __shfl_down(zs, off);
  if ((tid & 63) == 0) zred[tid >> 6] = zs;
  __syncthreads();
  const float zt = zred[0] + zred[1] + zred[2] + zred[3];
  const float z = 1.f / (1.f + __expf(-zt));

  const float* __restrict__ w9r  = W9  + (size_t)h * HH;
  const float* __restrict__ w10r = W10 + (size_t)h * HH;
  float gx = 0.f, gt = 0.f;
  for (int k = 0; k < HH; k += 4) {
    f4 a = *(const f4*)(w9r + k);
    f4 c = *(const f4*)(w10r + k);
    gx += cx[k] * a[0] + cx[k + 1] * a[1] + cx[k + 2] * a[2] + cx[k + 3] * a[3];
    gt += ct[k] * c[0] + ct[k + 1] * c[1] + ct[k + 2] * c[2] + ct[k + 3] * c[3];
  }
  out_ci[b * HH + h] = z * tanhf(gx) + (1.f - z) * tanhf(gt);
}

extern "C" void kernel_launch(void* const* d_in, const int* in_sizes, int n_in,
                              void* d_out, int out_size, void* d_ws, size_t ws_size,
                              hipStream_t stream) {
  const float* enc = (const float*)d_in[1];
  const float* h0  = (const float*)d_in[2];
  const float* ax  = (const float*)d_in[3];
  const float* W1  = (const float*)d_in[4];
  const float* W3  = (const float*)d_in[6];
  const float* W4  = (const float*)d_in[7];
  const float* W5  = (const float*)d_in[8];
  const float* W8  = (const float*)d_in[11];
  const float* W9  = (const float*)d_in[12];
  const float* W10 = (const float*)d_in[13];
  const float* W11 = (const float*)d_in[14];
  float* out = (float*)d_out;  // [0:B*H) ci, [B*H : 2*B*H) ax_new

  // Workspace layout (floats). W1c/W5c each 512*1024 bf16 = 262144 floats (1MB).
  // partx/partt ALIAS the Wc regions: Wc dead after e1_gemm; prep_all recreates
  // Wc at the start of every call (deterministic across graph replays).
  float* w = (float*)d_ws;
  unsigned short* W1c = (unsigned short*)w;            // floats [0, 262144)
  unsigned short* W5c = (unsigned short*)(w + 262144); // floats [262144, 524288)
  float* partx = w;                  // aliases W1c
  float* partt = w + 262144;         // aliases W5c
  float* e1s   = w + 524288;         // 32768 (transposed [b][s])
  float* e1t   = w + 557056;         // 32768 (transposed [b][t])
  float* axi   = w + 589824;         // 32768
  float* ati   = w + 622592;         // 32768
  float* cxi   = w + 655360;         // 32768
  float* cti   = w + 688128;         // 32768
  float* Cpoly = w + 720896;         // 16   (end: ~2.88 MB)

  prep_all<<<513, 256, 0, stream>>>(W1, W5, W3, W4, W1c, W5c, Cpoly);
  e1_gemm<<<M_TOT / 64, 512, 0, stream>>>(enc, h0, W1c, W5c, W4, W8, e1s, e1t);
  softmax_both<<<2 * BB, 256, 0, stream>>>(e1s, e1t, ax, Cpoly, axi, ati, out + BB * HH);
  wpart2<<<2 * BB * NCH, 256, 0, stream>>>(enc, h0, axi, ati, partx, partt);
  wreduce2<<<2 * BB * HH / 256, 256, 0, stream>>>(partx, partt, cxi, cti);
  ci_kernel<<<BB * 4, 256, 0, stream>>>(cxi, cti, W9, W10, W11, out);
}

// Round 17
// 209.380 us; speedup vs baseline: 1.6193x; 1.0333x over previous
//
#include <hip/hip_runtime.h>
#include <hip/hip_bf16.h>

#define HH 1024
#define AA 512
#define BB 32
#define SS 1024
#define TN 1024
#define M_ENC (SS*BB)
#define M_TOT ((SS+TN)*BB)
#define NCH 8

// e1_gemm LDS: A buffer = 2 halves x (64 rows x 64B) = 8KB; double-buffered.
#define ABUF 8192

typedef __attribute__((ext_vector_type(8))) short short8;
typedef __attribute__((ext_vector_type(4))) float f4;

union bfu { __hip_bfloat16 h; unsigned short u; };
__device__ __forceinline__ unsigned int f2bu(float x) {
  bfu t; t.h = __float2bfloat16(x); return (unsigned int)t.u;
}
__device__ __forceinline__ unsigned short f2b(float x) {
  bfu t; t.h = __float2bfloat16(x); return t.u;
}
__device__ __forceinline__ float tanh_fast(float x) {
  float e = __expf(2.f * x);
  return 1.f - 2.f / (e + 1.f);
}

// ---- merged prep: W1/W5 -> bf16 fragment-order repack + poly coefficients --
// blocks 0..255: W1; 256..511: W5; block 512: poly.
// Wc layout: frag id t = ((kb*32 + rg)*64 + lane), 8 bf16 per frag,
// fragment holds W[rg*16 + (lane&15)][kb*32 + (lane>>4)*8 + j].
__global__ void prep_all(const float* __restrict__ W1, const float* __restrict__ W5,
                         const float* __restrict__ W3, const float* __restrict__ W4,
                         unsigned short* __restrict__ W1c, unsigned short* __restrict__ W5c,
                         float* __restrict__ C) {
  if (blockIdx.x < 512) {
    const float* __restrict__ W = (blockIdx.x < 256) ? W1 : W5;
    unsigned short* __restrict__ Wc = (blockIdx.x < 256) ? W1c : W5c;
    const int t = (blockIdx.x & 255) * 256 + threadIdx.x;   // 0..65535
    const int lane = t & 63;
    const int rg = (t >> 6) & 31;
    const int kb = t >> 11;
    const int row = rg * 16 + (lane & 15);
    const int k = kb * 32 + ((lane >> 4) << 3);
    const float* src = W + (size_t)row * HH + k;
    f4 v0 = *(const f4*)(src);
    f4 v1 = *(const f4*)(src + 4);
    short8 o;
    o[0] = f2b(v0[0]); o[1] = f2b(v0[1]); o[2] = f2b(v0[2]); o[3] = f2b(v0[3]);
    o[4] = f2b(v1[0]); o[5] = f2b(v1[1]); o[6] = f2b(v1[2]); o[7] = f2b(v1[3]);
    *(short8*)(Wc + (size_t)t * 8) = o;
  } else {
    __shared__ float r1[256], r3[256], r5[256];
    const int tp = threadIdx.x;  // 256
    float s1 = 0.f, s3 = 0.f, s5 = 0.f;
    for (int a = tp; a < AA; a += 256) {
      const float w = W3[a], u = W4[2 * AA + a];
      const float w2 = w * w;
      s1 += u * w; s3 += u * w * w2; s5 += u * w * w2 * w2;
    }
    r1[tp] = s1; r3[tp] = s3; r5[tp] = s5;
    __syncthreads();
    for (int off = 128; off > 0; off >>= 1) {
      if (tp < off) { r1[tp] += r1[tp + off]; r3[tp] += r3[tp + off]; r5[tp] += r5[tp + off]; }
      __syncthreads();
    }
    if (tp == 0) { C[0] = r1[0]; C[1] = -r3[0] / 3.f; C[2] = r5[0] * (2.f / 15.f); }
  }
}

// ---- big fused GEMM: e1[row] = sum_a V[a]*tanh( X[row,:] . W[a,:] ) --------
// r13 configuration VERBATIM (best measured: e1 ~136us, VGPR 60, 0 spill,
// 0 conflicts). BM=64, 512 threads = 8 waves (1x8 col-groups), wave tile
// 64x64, acc[4][4], BK=64 (16 K-steps), 2 blocks/CU. A reg-staged one step
// ahead (0-conflict XOR layout); B 8 coalesced dwordx4/wave from L2-resident
// fragment-ordered Wc, same-step; barrier orders only A ds_writes
// (lgkmcnt(0) + raw s_barrier); block-parity K-stagger (koff).
__global__ __launch_bounds__(512, 4)
void e1_gemm(const float* __restrict__ enc, const float* __restrict__ h0,
             const unsigned short* __restrict__ W1c, const unsigned short* __restrict__ W5c,
             const float* __restrict__ W4, const float* __restrict__ W8,
             float* __restrict__ e1s, float* __restrict__ e1t) {
  const int wg   = blockIdx.x;        // 1024 blocks, 64 rows each
  const int tid  = threadIdx.x;       // 512
  const int lane = tid & 63;
  const int colg = tid >> 6;          // 0..7 (64-col group)
  const int l15  = lane & 15;
  const int lg   = lane >> 4;         // 0..3
  const int koff = (wg & 1) << 3;     // K-stagger: 0 or 8

  const bool is_enc = (wg * 64) < M_ENC;
  const float* __restrict__ Xg = is_enc ? enc : h0;
  const unsigned short* __restrict__ Wc = is_enc ? W1c : W5c;
  const float* __restrict__ Vg = is_enc ? W4 : W8;
  const int row0 = is_enc ? wg * 64 : wg * 64 - M_ENC;

  __shared__ char lds_raw[2 * ABUF];
  float* lred = (float*)lds_raw;      // [8][64] floats, epilogue only

  f4 acc[4][4];
#pragma unroll
  for (int i = 0; i < 4; ++i)
#pragma unroll
    for (int j = 0; j < 4; ++j) acc[i][j] = (f4){0.f, 0.f, 0.f, 0.f};

  // ---- A staging: thread -> (row, quad); 2 f4 loads + 2 8B ds_writes -------
  const int arow = tid >> 3;                     // 0..63
  const int aq   = tid & 7;                      // 0..7 (4 floats each)
  const float* ap = Xg + (size_t)(row0 + arow) * HH + aq * 4;
  const int slotS = (aq >> 1) ^ ((arow >> 1) & 3);
  const int aDst = arow * 64 + slotS * 16 + (aq & 1) * 8;

  // ---- A fragment read base (r9-r13 verified swizzle); + ks*4096 + rt*1024 --
  const int aRd = l15 * 64 + ((lg ^ ((l15 >> 1) & 3)) << 4);

  // ---- B: per-thread global base; step kb at +kb*64KB -----------------------
  const char* bp = (const char*)Wc + colg * 4096 + lane * 16;

  f4 an0, an1;                                   // A regs for NEXT step
  short8 bfr[8];                                 // B frags for CURRENT step

#define ALOAD(k_) do {                                                        \
    an0 = *(const f4*)(ap + (k_) * 64);                                       \
    an1 = *(const f4*)(ap + (k_) * 64 + 32);                                  \
  } while (0)

#define AWR(bo_) do {                                                         \
    uint2 o0_, o1_;                                                           \
    o0_.x = f2bu(an0[0]) | (f2bu(an0[1]) << 16);                              \
    o0_.y = f2bu(an0[2]) | (f2bu(an0[3]) << 16);                              \
    o1_.x = f2bu(an1[0]) | (f2bu(an1[1]) << 16);                              \
    o1_.y = f2bu(an1[2]) | (f2bu(an1[3]) << 16);                              \
    *(uint2*)(lds_raw + (bo_) + aDst) = o0_;                                  \
    *(uint2*)(lds_raw + (bo_) + 4096 + aDst) = o1_;                           \
  } while (0)

#define BLOAD(kb2_) do {                                                      \
    const char* b_ = bp + (size_t)(kb2_) * 65536;                             \
    _Pragma("unroll")                                                         \
    for (int q_ = 0; q_ < 8; ++q_)                                            \
      bfr[q_] = *(const short8*)(b_ + (q_ >> 2) * 32768 + (q_ & 3) * 1024);   \
  } while (0)

#define COMPUTE(bo_) do {                                                     \
    const char* base_ = lds_raw + (bo_);                                      \
    _Pragma("unroll")                                                         \
    for (int ks_ = 0; ks_ < 2; ++ks_) {                                       \
      __builtin_amdgcn_s_setprio(1);                                          \
      _Pragma("unroll")                                                       \
      for (int rt = 0; rt < 4; ++rt) {                                        \
        short8 af_ = *(const short8*)(base_ + ks_ * 4096 + aRd + rt * 1024);  \
        _Pragma("unroll")                                                     \
        for (int cf = 0; cf < 4; ++cf)                                        \
          acc[rt][cf] = __builtin_amdgcn_mfma_f32_16x16x32_bf16(              \
              af_, bfr[ks_ * 4 + cf], acc[rt][cf], 0, 0, 0);                  \
      }                                                                       \
      __builtin_amdgcn_s_setprio(0);                                          \
    }                                                                         \
  } while (0)

// barrier ordering ONLY LDS traffic; B/A global loads may stay in flight
#define SYNCA() do {                                                          \
    __builtin_amdgcn_sched_barrier(0);                                        \
    asm volatile("s_waitcnt lgkmcnt(0)" ::: "memory");                        \
    __builtin_amdgcn_s_barrier();                                             \
    __builtin_amdgcn_sched_barrier(0);                                        \
  } while (0)

  // ---- prologue -------------------------------------------------------------
  ALOAD(koff);
  AWR(0);                 // waits its own A loads (auto vmcnt)
  ALOAD((1 + koff) & 15); // next A in flight across the barrier
  SYNCA();                // publish buf0

  // ---- steps 0..13, unrolled x2 (static buffer offsets, staggered k) --------
#pragma unroll 1
  for (int it = 0; it < 7; ++it) {
    const int kc0 = (2 * it + koff) & 15;
    const int ka2 = (2 * it + 2 + koff) & 15;
    const int kc1 = (2 * it + 1 + koff) & 15;
    const int ka3 = (2 * it + 3 + koff) & 15;
    // even step: write A(next)->buf1, prefetch A(next+1), compute buf0
    AWR(ABUF); ALOAD(ka2); BLOAD(kc0); COMPUTE(0); SYNCA();
    // odd step: write A(next)->buf0, prefetch A(next+1), compute buf1
    AWR(0); ALOAD(ka3); BLOAD(kc1); COMPUTE(ABUF); SYNCA();
  }
  // step 14: write A(step15)->buf1 (held regs), compute buf0
  AWR(ABUF); BLOAD((14 + koff) & 15); COMPUTE(0); SYNCA();
  // step 15: compute buf1
  BLOAD((15 + koff) & 15); COMPUTE(ABUF);
#undef ALOAD
#undef AWR
#undef BLOAD
#undef COMPUTE
#undef SYNCA

  // epilogue: tanh, weight by V, reduce 16 col-lanes, then across col-groups
  float vvv[4];
#pragma unroll
  for (int cf = 0; cf < 4; ++cf) vvv[cf] = Vg[colg * 64 + cf * 16 + l15];

  __syncthreads();   // A buffers dead; lred aliases buf0
#pragma unroll
  for (int rt = 0; rt < 4; ++rt) {
    float ps[4] = {0.f, 0.f, 0.f, 0.f};
#pragma unroll
    for (int cf = 0; cf < 4; ++cf) {
      const float w = vvv[cf];
#pragma unroll
      for (int r = 0; r < 4; ++r) ps[r] += w * tanh_fast(acc[rt][cf][r]);
    }
#pragma unroll
    for (int r = 0; r < 4; ++r) {
#pragma unroll
      for (int off = 1; off < 16; off <<= 1) ps[r] += __shfl_xor(ps[r], off);
    }
    if (l15 == 0) {
#pragma unroll
      for (int r = 0; r < 4; ++r)
        lred[colg * 64 + rt * 16 + lg * 4 + r] = ps[r];
    }
  }
  __syncthreads();
  if (tid < 64) {
    float s = 0.f;
#pragma unroll
    for (int c = 0; c < 8; ++c) s += lred[c * 64 + tid];
    const int gr = row0 + tid;
    const int q = gr >> 5;            // s or t index
    const int b = gr & 31;
    if (is_enc) e1s[b * SS + q] = s;
    else        e1t[b * TN + q] = s;
  }
}

// ---------------- merged softmaxes: blocks 0..31 = s-side, 32..63 = t-side --
__global__ void softmax_both(const float* __restrict__ e1s, const float* __restrict__ e1t,
                             const float* __restrict__ ax, const float* __restrict__ C,
                             float* __restrict__ axi, float* __restrict__ ati,
                             float* __restrict__ axnew) {
  const int tid = threadIdx.x;  // 256
  __shared__ float red[256];
  if (blockIdx.x < BB) {
    const int b = blockIdx.x;
    const float c0 = C[0], c1 = C[1], c2 = C[2];
    float loc[4], xv[4];
    float m = -1e30f;
#pragma unroll
    for (int i = 0; i < 4; ++i) {
      const int s = i * 256 + tid;
      const float x = ax[b * SS + s];
      const float x2 = x * x;
      xv[i] = x;
      loc[i] = e1s[b * SS + s] + x * (c0 + x2 * (c1 + x2 * c2));
      m = fmaxf(m, loc[i]);
    }
    red[tid] = m; __syncthreads();
    for (int off = 128; off > 0; off >>= 1) {
      if (tid < off) red[tid] = fmaxf(red[tid], red[tid + off]);
      __syncthreads();
    }
    m = red[0]; __syncthreads();
    float sum = 0.f;
#pragma unroll
    for (int i = 0; i < 4; ++i) { loc[i] = __expf(loc[i] - m); sum += loc[i]; }
    red[tid] = sum; __syncthreads();
    for (int off = 128; off > 0; off >>= 1) {
      if (tid < off) red[tid] += red[tid + off];
      __syncthreads();
    }
    const float inv = 1.f / red[0];
#pragma unroll
    for (int i = 0; i < 4; ++i) {
      const int s = i * 256 + tid;
      const float a_ = loc[i] * inv;
      axi[b * SS + s] = a_;
      axnew[b * SS + s] = xv[i] + a_;
    }
  } else {
    const int b = blockIdx.x - BB;
    float loc[4];
    float m = -1e30f;
#pragma unroll
    for (int i = 0; i < 4; ++i) { loc[i] = e1t[b * TN + i * 256 + tid]; m = fmaxf(m, loc[i]); }
    red[tid] = m; __syncthreads();
    for (int off = 128; off > 0; off >>= 1) {
      if (tid < off) red[tid] = fmaxf(red[tid], red[tid + off]);
      __syncthreads();
    }
    m = red[0]; __syncthreads();
    float sum = 0.f;
#pragma unroll
    for (int i = 0; i < 4; ++i) { loc[i] = __expf(loc[i] - m); sum += loc[i]; }
    red[tid] = sum; __syncthreads();
    for (int off = 128; off > 0; off >>= 1) {
      if (tid < off) red[tid] += red[tid + off];
      __syncthreads();
    }
    const float inv = 1.f / red[0];
#pragma unroll
    for (int i = 0; i < 4; ++i) ati[b * TN + (i * 256 + tid)] = loc[i] * inv;
  }
}

// ---------------- merged chunked weighted sums (x and t streams) ------------
__global__ void wpart2(const float* __restrict__ enc, const float* __restrict__ h0,
                       const float* __restrict__ axi, const float* __restrict__ ati,
                       float* __restrict__ partx, float* __restrict__ partt) {
  const int gb = blockIdx.x;                 // 0..511
  const bool isx = gb < BB * NCH;
  const float* __restrict__ X = isx ? enc : h0;
  const float* __restrict__ w = isx ? axi : ati;
  float* __restrict__ part = isx ? partx : partt;
  const int idx = isx ? gb : gb - BB * NCH;
  const int b = idx / NCH, ch = idx % NCH;
  const int tid = threadIdx.x;  // 256, each handles 4 h
  __shared__ float ws[SS / NCH];
  if (tid < SS / NCH) ws[tid] = w[b * SS + ch * (SS / NCH) + tid];
  __syncthreads();
  f4 acc = (f4){0.f, 0.f, 0.f, 0.f};
  const float* base = X + ((size_t)(ch * (SS / NCH)) * BB + b) * HH + tid * 4;
#pragma unroll 4
  for (int i = 0; i < SS / NCH; ++i) {
    f4 x = *(const f4*)(base + (size_t)i * BB * HH);
    acc += ws[i] * x;
  }
  *(f4*)&part[((size_t)(b * NCH + ch)) * HH + tid * 4] = acc;
}

__global__ void wreduce2(const float* __restrict__ partx, const float* __restrict__ partt,
                         float* __restrict__ cxi, float* __restrict__ cti) {
  const int idx = blockIdx.x * 256 + threadIdx.x;  // over 2*B*H
  const bool isx = idx < BB * HH;
  const float* __restrict__ part = isx ? partx : partt;
  float* __restrict__ outp = isx ? cxi : cti;
  const int j = isx ? idx : idx - BB * HH;
  const int b = j / HH, h = j % HH;
  float s = 0.f;
#pragma unroll
  for (int ch = 0; ch < NCH; ++ch) s += part[((size_t)(b * NCH + ch)) * HH + h];
  outp[j] = s;
}

// ---- ci[b,h] = z*tanh(cxi.W9[h,:]) + (1-z)*tanh(cti.W10[h,:]), z fused ----
__global__ void ci_kernel(const float* __restrict__ cxi, const float* __restrict__ cti,
                          const float* __restrict__ W9, const float* __restrict__ W10,
                          const float* __restrict__ W11, float* __restrict__ out_ci) {
  const int b = blockIdx.x >> 2, hb = blockIdx.x & 3, tid = threadIdx.x;
  const int h = hb * 256 + tid;
  __shared__ float cx[HH], ct[HH];
  __shared__ float zred[4];
  for (int i = tid; i < HH; i += 256) { cx[i] = cxi[b * HH + i]; ct[i] = cti[b * HH + i]; }
  __syncthreads();
  float zs = 0.f;
  for (int i = tid; i < HH; i += 256) zs += cx[i] * W11[i] + ct[i] * W11[HH + i];
  for (int off = 32; off > 0; off >>= 1) zs += __shfl_down(zs, off);
  if ((tid & 63) == 0) zred[tid >> 6] = zs;
  __syncthreads();
  const float zt = zred[0] + zred[1] + zred[2] + zred[3];
  const float z = 1.f / (1.f + __expf(-zt));

  const float* __restrict__ w9r  = W9  + (size_t)h * HH;
  const float* __restrict__ w10r = W10 + (size_t)h * HH;
  float gx = 0.f, gt = 0.f;
  for (int k = 0; k < HH; k += 4) {
    f4 a = *(const f4*)(w9r + k);
    f4 c = *(const f4*)(w10r + k);
    gx += cx[k] * a[0] + cx[k + 1] * a[1] + cx[k + 2] * a[2] + cx[k + 3] * a[3];
    gt += ct[k] * c[0] + ct[k + 1] * c[1] + ct[k + 2] * c[2] + ct[k + 3] * c[3];
  }
  out_ci[b * HH + h] = z * tanhf(gx) + (1.f - z) * tanhf(gt);
}

extern "C" void kernel_launch(void* const* d_in, const int* in_sizes, int n_in,
                              void* d_out, int out_size, void* d_ws, size_t ws_size,
                              hipStream_t stream) {
  const float* enc = (const float*)d_in[1];
  const float* h0  = (const float*)d_in[2];
  const float* ax  = (const float*)d_in[3];
  const float* W1  = (const float*)d_in[4];
  const float* W3  = (const float*)d_in[6];
  const float* W4  = (const float*)d_in[7];
  const float* W5  = (const float*)d_in[8];
  const float* W8  = (const float*)d_in[11];
  const float* W9  = (const float*)d_in[12];
  const float* W10 = (const float*)d_in[13];
  const float* W11 = (const float*)d_in[14];
  float* out = (float*)d_out;  // [0:B*H) ci, [B*H : 2*B*H) ax_new

  // Workspace layout (floats). W1c/W5c each 512*1024 bf16 = 262144 floats (1MB).
  // partx/partt ALIAS the Wc regions: Wc dead after e1_gemm; prep_all recreates
  // Wc at the start of every call (deterministic across graph replays).
  float* w = (float*)d_ws;
  unsigned short* W1c = (unsigned short*)w;            // floats [0, 262144)
  unsigned short* W5c = (unsigned short*)(w + 262144); // floats [262144, 524288)
  float* partx = w;                  // aliases W1c
  float* partt = w + 262144;         // aliases W5c
  float* e1s   = w + 524288;         // 32768 (transposed [b][s])
  float* e1t   = w + 557056;         // 32768 (transposed [b][t])
  float* axi   = w + 589824;         // 32768
  float* ati   = w + 622592;         // 32768
  float* cxi   = w + 655360;         // 32768
  float* cti   = w + 688128;         // 32768
  float* Cpoly = w + 720896;         // 16   (end: ~2.88 MB)

  prep_all<<<513, 256, 0, stream>>>(W1, W5, W3, W4, W1c, W5c, Cpoly);
  e1_gemm<<<M_TOT / 64, 512, 0, stream>>>(enc, h0, W1c, W5c, W4, W8, e1s, e1t);
  softmax_both<<<2 * BB, 256, 0, stream>>>(e1s, e1t, ax, Cpoly, axi, ati, out + BB * HH);
  wpart2<<<2 * BB * NCH, 256, 0, stream>>>(enc, h0, axi, ati, partx, partt);
  wreduce2<<<2 * BB * HH / 256, 256, 0, stream>>>(partx, partt, cxi, cti);
  ci_kernel<<<BB * 4, 256, 0, stream>>>(cxi, cti, W9, W10, W11, out);
}